// Round 4
// baseline (238.915 us; speedup 1.0000x reference)
//
#include <hip/hip_runtime.h>

#define N_ITEMS 100000
#define HID 128
#define NNZ_T 1600000
#define EPW 128        // edges per wave in spmm
#define BATCH 8        // gather batch (software pipeline stage)
#define NBATCH (EPW / BATCH)

typedef unsigned short ushort_t;
typedef unsigned int uint_t;
typedef short bf16x8 __attribute__((ext_vector_type(8)));
typedef float f32x4 __attribute__((ext_vector_type(4)));

static __device__ __forceinline__ ushort_t f32_to_bf16(float f) {
    uint_t u = __float_as_uint(f);
    uint_t r = (u + 0x7FFFu + ((u >> 16) & 1u)) >> 16;   // RNE
    return (ushort_t)r;
}

// --- prep: W fp32 [128][128] row-major -> bf16 same layout (B operand of X*W^T) ---
__global__ void prep_w(const float* __restrict__ W, ushort_t* __restrict__ Wb) {
    int i = blockIdx.x * blockDim.x + threadIdx.x;   // 0..16383
    Wb[i] = f32_to_bf16(W[i]);
}

// --- support = X @ W^T + b via MFMA 16x16x32 bf16, stored bf16 ---
// (unchanged from round 3 — passed, ~invisible in profile)
__global__ __launch_bounds__(256) void gemm_mfma(
    const float* __restrict__ X, const ushort_t* __restrict__ Wb,
    const float* __restrict__ bias, ushort_t* __restrict__ S) {
    const int lane = threadIdx.x & 63;
    const int wave = threadIdx.x >> 6;
    const int m = lane & 15;
    const int q = lane >> 4;
    const int row0 = blockIdx.x * 64 + wave * 16;

    int arow = row0 + m;
    if (arow >= N_ITEMS) arow = N_ITEMS - 1;          // clamp (stores guarded)

    f32x4 acc[8] = {};

#pragma unroll
    for (int kb = 0; kb < 4; ++kb) {
        const int k0 = kb * 32 + q * 8;
        float4 a0 = *(const float4*)&X[(size_t)arow * HID + k0];
        float4 a1 = *(const float4*)&X[(size_t)arow * HID + k0 + 4];
        bf16x8 af;
        af[0] = (short)f32_to_bf16(a0.x); af[1] = (short)f32_to_bf16(a0.y);
        af[2] = (short)f32_to_bf16(a0.z); af[3] = (short)f32_to_bf16(a0.w);
        af[4] = (short)f32_to_bf16(a1.x); af[5] = (short)f32_to_bf16(a1.y);
        af[6] = (short)f32_to_bf16(a1.z); af[7] = (short)f32_to_bf16(a1.w);
#pragma unroll
        for (int nt = 0; nt < 8; ++nt) {
            bf16x8 bfr = *(const bf16x8*)&Wb[(size_t)(nt * 16 + m) * HID + k0];
            acc[nt] = __builtin_amdgcn_mfma_f32_16x16x32_bf16(af, bfr, acc[nt], 0, 0, 0);
        }
    }

#pragma unroll
    for (int nt = 0; nt < 8; ++nt) {
        const int col = nt * 16 + m;
        const float bv = bias[col];
#pragma unroll
        for (int r = 0; r < 4; ++r) {
            const int row = row0 + q * 4 + r;
            if (row < N_ITEMS)
                S[(size_t)row * HID + col] = f32_to_bf16(acc[nt][r] + bv);
        }
    }
}

// --- out = A_coo @ S: one wave per 128-edge chunk, lane owns 2 columns ---
// Edge streams (rows/cols/vals) read at wave-uniform addresses (e0 derived from
// readfirstlane -> provably uniform -> scalar cache), no LDS, no syncthreads.
// Gathers software-double-buffered: batch g+1 issued before consuming batch g.
// Rows globally sorted: interior runs exclusive -> plain store; chunk-boundary
// runs -> atomicAdd.
__global__ __launch_bounds__(256) void spmm(
    const int* __restrict__ rows, const int* __restrict__ cols,
    const float* __restrict__ vals, const ushort_t* __restrict__ S,
    float* __restrict__ out) {
    const int lane = threadIdx.x & 63;
    const int wv = __builtin_amdgcn_readfirstlane(threadIdx.x >> 6);
    const int e0 = (blockIdx.x * 4 + wv) * EPW;

    int    rA[BATCH], cA[BATCH]; float vA[BATCH]; uint_t uA[BATCH];
    int    rB[BATCH], cB[BATCH]; float vB[BATCH]; uint_t uB[BATCH];

    float2 acc = make_float2(0.f, 0.f);
    int cur;
    bool first = true;

    auto fetch = [&](int g, int* r, int* c, float* v, uint_t* u) {
        const int eb = e0 + g * BATCH;
#pragma unroll
        for (int j = 0; j < BATCH; ++j) {
            r[j] = rows[eb + j];
            c[j] = cols[eb + j];
            v[j] = vals[eb + j];
        }
#pragma unroll
        for (int j = 0; j < BATCH; ++j)
            u[j] = *(const uint_t*)&S[(size_t)c[j] * HID + 2 * lane];
    };
    auto consume = [&](const int* r, const float* v, const uint_t* u) {
#pragma unroll
        for (int j = 0; j < BATCH; ++j) {
            if (r[j] != cur) {           // wave-uniform scalar branch
                float* p = &out[(size_t)cur * HID + 2 * lane];
                if (first) { atomicAdd(p, acc.x); atomicAdd(p + 1, acc.y); }
                else       { *(float2*)p = acc; }   // interior run: exclusive
                first = false;
                acc = make_float2(0.f, 0.f);
                cur = r[j];
            }
            const float f0 = __uint_as_float(u[j] << 16);
            const float f1 = __uint_as_float(u[j] & 0xFFFF0000u);
            acc.x = fmaf(v[j], f0, acc.x);
            acc.y = fmaf(v[j], f1, acc.y);
        }
    };

    fetch(0, rA, cA, vA, uA);
    cur = rA[0];
    for (int g = 0; g < NBATCH; g += 2) {
        if (g + 1 < NBATCH) fetch(g + 1, rB, cB, vB, uB);
        consume(rA, vA, uA);
        if (g + 2 < NBATCH) fetch(g + 2, rA, cA, vA, uA);
        consume(rB, vB, uB);
    }
    float* p = &out[(size_t)cur * HID + 2 * lane];   // last run may continue on
    atomicAdd(p, acc.x); atomicAdd(p + 1, acc.y);
}

extern "C" void kernel_launch(void* const* d_in, const int* in_sizes, int n_in,
                              void* d_out, int out_size, void* d_ws, size_t ws_size,
                              hipStream_t stream) {
    const float* X    = (const float*)d_in[0];
    const int*   rows = (const int*)  d_in[1];
    const int*   cols = (const int*)  d_in[2];
    const float* vals = (const float*)d_in[3];
    const float* W    = (const float*)d_in[4];
    const float* bias = (const float*)d_in[5];
    float* out = (float*)d_out;

    ushort_t* Wb = (ushort_t*)d_ws;                    // 32 KB
    ushort_t* S  = Wb + HID * HID;                     // 25.6 MB bf16

    hipMemsetAsync(d_out, 0, (size_t)out_size * sizeof(float), stream);
    prep_w<<<(HID * HID) / 256, 256, 0, stream>>>(W, Wb);
    gemm_mfma<<<(N_ITEMS + 63) / 64, 256, 0, stream>>>(X, Wb, bias, S);
    spmm<<<NNZ_T / (4 * EPW), 256, 0, stream>>>(rows, cols, vals, S, out);
}

// Round 5
// 222.552 us; speedup vs baseline: 1.0735x; 1.0735x over previous
//
#include <hip/hip_runtime.h>

#define N_ITEMS 100000
#define HID 128
#define NNZ_T 1600000

typedef unsigned short ushort_t;
typedef unsigned int uint_t;
typedef short bf16x8 __attribute__((ext_vector_type(8)));
typedef float f32x4 __attribute__((ext_vector_type(4)));

static __device__ __forceinline__ ushort_t f32_to_bf16(float f) {
    uint_t u = __float_as_uint(f);
    uint_t r = (u + 0x7FFFu + ((u >> 16) & 1u)) >> 16;   // RNE
    return (ushort_t)r;
}

// --- prep: W fp32 [128][128] row-major -> bf16 same layout ---
__global__ void prep_w(const float* __restrict__ W, ushort_t* __restrict__ Wb) {
    int i = blockIdx.x * blockDim.x + threadIdx.x;
    Wb[i] = f32_to_bf16(W[i]);
}

// --- row_ptr[r] = lower_bound(rows, r); rows sorted ascending ---
__global__ void build_rowptr(const int* __restrict__ rows, int* __restrict__ row_ptr) {
    int r = blockIdx.x * blockDim.x + threadIdx.x;
    if (r > N_ITEMS) return;
    int lo = 0, hi = NNZ_T;
    while (lo < hi) {
        int mid = (lo + hi) >> 1;
        if (rows[mid] < r) lo = mid + 1; else hi = mid;
    }
    row_ptr[r] = lo;
}

// --- support = X @ W^T + b via MFMA 16x16x32 bf16, stored bf16 (unchanged) ---
__global__ __launch_bounds__(256) void gemm_mfma(
    const float* __restrict__ X, const ushort_t* __restrict__ Wb,
    const float* __restrict__ bias, ushort_t* __restrict__ S) {
    const int lane = threadIdx.x & 63;
    const int wave = threadIdx.x >> 6;
    const int m = lane & 15;
    const int q = lane >> 4;
    const int row0 = blockIdx.x * 64 + wave * 16;

    int arow = row0 + m;
    if (arow >= N_ITEMS) arow = N_ITEMS - 1;          // clamp (stores guarded)

    f32x4 acc[8] = {};

#pragma unroll
    for (int kb = 0; kb < 4; ++kb) {
        const int k0 = kb * 32 + q * 8;
        float4 a0 = *(const float4*)&X[(size_t)arow * HID + k0];
        float4 a1 = *(const float4*)&X[(size_t)arow * HID + k0 + 4];
        bf16x8 af;
        af[0] = (short)f32_to_bf16(a0.x); af[1] = (short)f32_to_bf16(a0.y);
        af[2] = (short)f32_to_bf16(a0.z); af[3] = (short)f32_to_bf16(a0.w);
        af[4] = (short)f32_to_bf16(a1.x); af[5] = (short)f32_to_bf16(a1.y);
        af[6] = (short)f32_to_bf16(a1.z); af[7] = (short)f32_to_bf16(a1.w);
#pragma unroll
        for (int nt = 0; nt < 8; ++nt) {
            bf16x8 bfr = *(const bf16x8*)&Wb[(size_t)(nt * 16 + m) * HID + k0];
            acc[nt] = __builtin_amdgcn_mfma_f32_16x16x32_bf16(af, bfr, acc[nt], 0, 0, 0);
        }
    }

#pragma unroll
    for (int nt = 0; nt < 8; ++nt) {
        const int col = nt * 16 + m;
        const float bv = bias[col];
#pragma unroll
        for (int r = 0; r < 4; ++r) {
            const int row = row0 + q * 4 + r;
            if (row < N_ITEMS)
                S[(size_t)row * HID + col] = f32_to_bf16(acc[nt][r] + bv);
        }
    }
}

// --- out[row] = sum_e vals[e] * S[cols[e]] over the row's CSR segment ---
// One WAVE per output row; lane owns 2 columns (uint = 2 bf16; 256B/wave/edge
// coalesced gather). No atomics, no branches in the hot loop, one float2 store.
// Rows with no edges store zeros -> no d_out memset needed.
__global__ __launch_bounds__(256) void spmm_csr(
    const int* __restrict__ cols, const float* __restrict__ vals,
    const int* __restrict__ row_ptr, const ushort_t* __restrict__ S,
    float* __restrict__ out) {
    const int lane = threadIdx.x & 63;
    const int row = blockIdx.x * 4 + (int)__builtin_amdgcn_readfirstlane(threadIdx.x >> 6);
    if (row >= N_ITEMS) return;

    const int p0 = row_ptr[row];
    const int p1 = row_ptr[row + 1];

    float2 acc = make_float2(0.f, 0.f);
    int p = p0;
    for (; p + 8 <= p1; p += 8) {
        uint_t u[8]; float v[8];
#pragma unroll
        for (int j = 0; j < 8; ++j) {         // 8 independent gathers in flight
            int c = cols[p + j];
            v[j] = vals[p + j];
            u[j] = *(const uint_t*)&S[(size_t)c * HID + 2 * lane];
        }
#pragma unroll
        for (int j = 0; j < 8; ++j) {
            acc.x = fmaf(v[j], __uint_as_float(u[j] << 16), acc.x);
            acc.y = fmaf(v[j], __uint_as_float(u[j] & 0xFFFF0000u), acc.y);
        }
    }
    for (; p < p1; ++p) {                     // remainder (<8 edges)
        int c = cols[p];
        float v = vals[p];
        uint_t u = *(const uint_t*)&S[(size_t)c * HID + 2 * lane];
        acc.x = fmaf(v, __uint_as_float(u << 16), acc.x);
        acc.y = fmaf(v, __uint_as_float(u & 0xFFFF0000u), acc.y);
    }
    *(float2*)&out[(size_t)row * HID + 2 * lane] = acc;
}

extern "C" void kernel_launch(void* const* d_in, const int* in_sizes, int n_in,
                              void* d_out, int out_size, void* d_ws, size_t ws_size,
                              hipStream_t stream) {
    const float* X    = (const float*)d_in[0];
    const int*   rows = (const int*)  d_in[1];
    const int*   cols = (const int*)  d_in[2];
    const float* vals = (const float*)d_in[3];
    const float* W    = (const float*)d_in[4];
    const float* bias = (const float*)d_in[5];
    float* out = (float*)d_out;

    ushort_t* Wb      = (ushort_t*)d_ws;                 // 32 KB
    ushort_t* S       = Wb + HID * HID;                  // 25.6 MB bf16
    int*      row_ptr = (int*)(S + (size_t)N_ITEMS * HID);  // 400 KB

    prep_w<<<(HID * HID) / 256, 256, 0, stream>>>(W, Wb);
    build_rowptr<<<(N_ITEMS + 256) / 256, 256, 0, stream>>>(rows, row_ptr);
    gemm_mfma<<<(N_ITEMS + 63) / 64, 256, 0, stream>>>(X, Wb, bias, S);
    spmm_csr<<<(N_ITEMS + 3) / 4, 256, 0, stream>>>(cols, vals, row_ptr, S, out);
}